// Round 4
// baseline (2415.004 us; speedup 1.0000x reference)
//
#include <hip/hip_runtime.h>
#include <math.h>

// GraphSAGE-mean 2-layer. Bucket-sorted edge list + per-bucket LDS accumulation
// (no CSR, no global float atomics) + bf16 gather tables (one 64B line per row).
//
// Fast path:
//   bhist (edges per 512-node bucket) -> bscan -> featb (f32->bf16 padded-32 rows) ->
//   bin (LDS multi-split, coalesced writes, packs (dst_local<<18)|src) ->
//   agg1 (per-bucket LDS acc[512][26] += bf16 gather of feat; counts deg; writes mean + dinv) ->
//   node_mlp (h1 = relu(feat@W1s + mean@W1n + b1); out = h1@W2s + b2; t2b = bf16(h1@W2n)) ->
//   agg2 (per-bucket LDS acc[512][24] += bf16 gather of t2; fused out=log_softmax(out+mean)).
// Layer-2 trick: aggregate h1@W2_neigh (24 dims) instead of h1 (40) — mean commutes with linear.

typedef long long ll;
typedef unsigned int u32;
typedef unsigned short u16;

__device__ inline u16 f2bf(float f) {
    u32 u = __builtin_bit_cast(u32, f);
    u32 r = (u + 0x7FFFu + ((u >> 16) & 1u)) >> 16;
    return (u16)r;
}
__device__ inline float bf2f(u16 h) {
    u32 u = ((u32)h) << 16;
    return __builtin_bit_cast(float, u);
}

#define BSHIFT 9
#define BNODES 512
#define BCHUNK 8192

// ---------------- bucket histogram + scan ----------------

__global__ void __launch_bounds__(512) bhist_kernel(const int* __restrict__ dst,
                                                    int* __restrict__ bcnt, int n_edges, int nb) {
    __shared__ int cnt[512];
    int t = threadIdx.x;
    cnt[t] = 0;
    __syncthreads();
    int base = blockIdx.x * BCHUNK;
#pragma unroll
    for (int j = 0; j < BCHUNK / 512; j++) {
        int i = base + t + j * 512;
        if (i < n_edges) atomicAdd(&cnt[dst[i] >> BSHIFT], 1);
    }
    __syncthreads();
    if (t < nb && cnt[t]) atomicAdd(&bcnt[t], cnt[t]);
}

__global__ void __launch_bounds__(512) bscan_kernel(const int* __restrict__ bcnt,
                                                    int* __restrict__ bstart, int* __restrict__ bcur, int nb) {
    __shared__ int lds[512];
    int t = threadIdx.x;
    int v = (t < nb) ? bcnt[t] : 0;
    lds[t] = v;
    __syncthreads();
    for (int off = 1; off < 512; off <<= 1) {
        int tv = (t >= off) ? lds[t - off] : 0;
        __syncthreads();
        lds[t] += tv;
        __syncthreads();
    }
    int excl = lds[t] - v;
    if (t < nb) { bstart[t] = excl; bcur[t] = excl; }
}

// ---------------- feat -> bf16 padded table ----------------

__global__ void featb_kernel(const float* __restrict__ feat, u16* __restrict__ featb, int total) {
    int i = blockIdx.x * 256 + threadIdx.x;
    if (i >= total) return;
    int n = i >> 5, c = i & 31;
    featb[i] = (c < 26) ? f2bf(feat[n * 26 + c]) : (u16)0;
}

// ---------------- bin: LDS multi-split into NB buckets ----------------

__global__ void __launch_bounds__(512) bin_kernel(const int* __restrict__ src, const int* __restrict__ dst,
                                                  int* __restrict__ bcur, u32* __restrict__ ebuf,
                                                  int n_edges, int nb) {
    __shared__ int cnt[512];    // counts, then reused as running cursors
    __shared__ int sc[512];     // scan workspace
    __shared__ int loff[512];   // exclusive offsets (stable copy)
    __shared__ int gbase[512];
    __shared__ u32 stage[BCHUNK];
    int t = threadIdx.x;
    int base = blockIdx.x * BCHUNK;
    cnt[t] = 0;
    __syncthreads();
#pragma unroll
    for (int j = 0; j < BCHUNK / 512; j++) {
        int i = base + t + j * 512;
        if (i < n_edges) atomicAdd(&cnt[dst[i] >> BSHIFT], 1);
    }
    __syncthreads();
    int v = cnt[t];
    sc[t] = v;
    __syncthreads();
    for (int off = 1; off < 512; off <<= 1) {
        int tv = (t >= off) ? sc[t - off] : 0;
        __syncthreads();
        sc[t] += tv;
        __syncthreads();
    }
    int excl = sc[t] - v;
    loff[t] = excl;
    if (t < nb && v) gbase[t] = atomicAdd(&bcur[t], v);
    __syncthreads();
    cnt[t] = excl;  // running cursor for stage placement
    __syncthreads();
#pragma unroll
    for (int j = 0; j < BCHUNK / 512; j++) {
        int i = base + t + j * 512;
        if (i < n_edges) {
            int d = dst[i];
            int b = d >> BSHIFT;
            u32 u = ((u32)(d & (BNODES - 1)) << 18) | (u32)src[i];
            int p = atomicAdd(&cnt[b], 1);
            stage[p] = u;
        }
    }
    __syncthreads();
    int total = min(n_edges - base, BCHUNK);
    for (int i = t; i < total; i += 512) {
        int lo = 0, hi = nb - 1;
        while (lo < hi) { int mid = (lo + hi + 1) >> 1; if (i >= loff[mid]) lo = mid; else hi = mid - 1; }
        ebuf[gbase[lo] + (i - loff[lo])] = stage[i];
    }
}

// ---------------- agg1: per-bucket LDS accumulation of feat (26 cols) + degree ----------------

__global__ void __launch_bounds__(512) agg1_kernel(const u16* __restrict__ featb, const u32* __restrict__ ebuf,
                                                   const int* __restrict__ bstart, const int* __restrict__ bend,
                                                   float* __restrict__ meanbuf, float* __restrict__ dinvg,
                                                   int n_nodes) {
    __shared__ float acc[BNODES * 26];
    __shared__ int degc[BNODES];
    int t = threadIdx.x;
    for (int i = t; i < BNODES * 26; i += 512) acc[i] = 0.0f;
    degc[t] = 0;
    __syncthreads();
    int b = blockIdx.x;
    int start = bstart[b];
    int end = bend[b];
    int lane = t & 63;
    int wave = t >> 6;
    int c = lane & 31;
    for (int k = start + wave * 64; k < end; k += 64 * 8) {
        int idx = k + lane;
        u32 w = (idx < end) ? ebuf[idx] : 0u;
        int cnt = min(end - k, 64);
        int half = (lane >= 32) ? 32 : 0;
        if (cnt == 64) {
#pragma unroll 8
            for (int j = 0; j < 32; j++) {
                u32 u = (u32)__shfl((int)w, j, 32);
                int dl = (int)(u >> 18);
                int sidx = (int)(u & 0x3FFFFu);
                if (c < 26) {
                    float f = bf2f(featb[(sidx << 5) + c]);
                    atomicAdd(&acc[dl * 26 + c], f);
                } else if (c == 26) {
                    atomicAdd(&degc[dl], 1);
                }
            }
        } else {
            for (int j = 0; j < 32; j++) {
                if (half + j >= cnt) break;
                u32 u = (u32)__shfl((int)w, j, 32);
                int dl = (int)(u >> 18);
                int sidx = (int)(u & 0x3FFFFu);
                if (c < 26) {
                    float f = bf2f(featb[(sidx << 5) + c]);
                    atomicAdd(&acc[dl * 26 + c], f);
                } else if (c == 26) {
                    atomicAdd(&degc[dl], 1);
                }
            }
        }
    }
    __syncthreads();
    int node0 = b << BSHIFT;
    int nloc = min(BNODES, n_nodes - node0);
    if (t < nloc) {
        int dg = degc[t];
        dinvg[node0 + t] = dg > 0 ? 1.0f / (float)dg : 0.0f;
    }
    int totf = nloc * 26;
    for (int i = t; i < totf; i += 512) {
        int loc = i / 26;
        int dg = degc[loc];
        float dinv = dg > 0 ? 1.0f / (float)dg : 0.0f;
        meanbuf[node0 * 26 + i] = acc[i] * dinv;
    }
}

// ---------------- node MLP: fused 2-layer self paths ----------------

__global__ void __launch_bounds__(256) node_mlp_kernel(
        const float* __restrict__ feat, const float* __restrict__ meanbuf,
        const float* __restrict__ W1s, const float* __restrict__ W1n, const float* __restrict__ b1,
        const float* __restrict__ W2s, const float* __restrict__ W2n, const float* __restrict__ b2,
        float* __restrict__ outp, u16* __restrict__ t2b, int n_nodes) {
    __shared__ float sW1s[26 * 40];
    __shared__ float sW1n[26 * 40];
    __shared__ float sW2s[40 * 24];
    __shared__ float sW2n[40 * 24];
    __shared__ float sb1[40];
    __shared__ float sb2[24];
    int t = threadIdx.x;
    for (int i = t; i < 26 * 40; i += 256) { sW1s[i] = W1s[i]; sW1n[i] = W1n[i]; }
    for (int i = t; i < 40 * 24; i += 256) { sW2s[i] = W2s[i]; sW2n[i] = W2n[i]; }
    if (t < 40) sb1[t] = b1[t];
    if (t < 24) sb2[t] = b2[t];
    __syncthreads();

    int n = blockIdx.x * 256 + t;
    if (n >= n_nodes) return;

    float h[40];
#pragma unroll
    for (int j = 0; j < 40; j++) h[j] = sb1[j];

    const float* fr = feat + n * 26;
    const float* br = meanbuf + n * 26;
#pragma unroll
    for (int k = 0; k < 26; k++) {
        float f = fr[k];
        float a = br[k];
#pragma unroll
        for (int j = 0; j < 40; j++) h[j] += f * sW1s[k * 40 + j] + a * sW1n[k * 40 + j];
    }
#pragma unroll
    for (int j = 0; j < 40; j++) h[j] = h[j] > 0.0f ? h[j] : 0.0f;

    float o[24], tt[24];
#pragma unroll
    for (int j = 0; j < 24; j++) { o[j] = sb2[j]; tt[j] = 0.0f; }
#pragma unroll
    for (int k = 0; k < 40; k++) {
        float hv = h[k];
#pragma unroll
        for (int j = 0; j < 24; j++) {
            o[j]  += hv * sW2s[k * 24 + j];
            tt[j] += hv * sW2n[k * 24 + j];
        }
    }
    float* op = outp + n * 24;
#pragma unroll
    for (int j = 0; j < 24; j++) op[j] = o[j];
    u16* tp = t2b + (n << 5);
#pragma unroll
    for (int j = 0; j < 24; j++) tp[j] = f2bf(tt[j]);
}

// ---------------- agg2: per-bucket LDS accumulation of t2 (24 cols) + fused log_softmax ----------------

__global__ void __launch_bounds__(512) agg2_kernel(const u16* __restrict__ t2b, const u32* __restrict__ ebuf,
                                                   const int* __restrict__ bstart, const int* __restrict__ bend,
                                                   const float* __restrict__ dinvg, float* __restrict__ outp,
                                                   int n_nodes) {
    __shared__ float acc[BNODES * 24];
    int t = threadIdx.x;
    for (int i = t; i < BNODES * 24; i += 512) acc[i] = 0.0f;
    __syncthreads();
    int b = blockIdx.x;
    int start = bstart[b];
    int end = bend[b];
    int lane = t & 63;
    int wave = t >> 6;
    int c = lane & 31;
    for (int k = start + wave * 64; k < end; k += 64 * 8) {
        int idx = k + lane;
        u32 w = (idx < end) ? ebuf[idx] : 0u;
        int cnt = min(end - k, 64);
        int half = (lane >= 32) ? 32 : 0;
        if (cnt == 64) {
#pragma unroll 8
            for (int j = 0; j < 32; j++) {
                u32 u = (u32)__shfl((int)w, j, 32);
                int dl = (int)(u >> 18);
                int sidx = (int)(u & 0x3FFFFu);
                if (c < 24) {
                    float f = bf2f(t2b[(sidx << 5) + c]);
                    atomicAdd(&acc[dl * 24 + c], f);
                }
            }
        } else {
            for (int j = 0; j < 32; j++) {
                if (half + j >= cnt) break;
                u32 u = (u32)__shfl((int)w, j, 32);
                int dl = (int)(u >> 18);
                int sidx = (int)(u & 0x3FFFFu);
                if (c < 24) {
                    float f = bf2f(t2b[(sidx << 5) + c]);
                    atomicAdd(&acc[dl * 24 + c], f);
                }
            }
        }
    }
    __syncthreads();
    int node0 = b << BSHIFT;
    int nloc = min(BNODES, n_nodes - node0);
    if (t < nloc) {
        int g = node0 + t;
        float dinv = dinvg[g];
        float* op = outp + g * 24;
        float4* op4 = reinterpret_cast<float4*>(op);
        const float4* ac4 = reinterpret_cast<const float4*>(acc + t * 24);
        float4 v[6];
        float m = -3.4e38f;
#pragma unroll
        for (int q = 0; q < 6; q++) {
            float4 o = op4[q];
            float4 a = ac4[q];
            v[q].x = o.x + a.x * dinv; v[q].y = o.y + a.y * dinv;
            v[q].z = o.z + a.z * dinv; v[q].w = o.w + a.w * dinv;
            m = fmaxf(m, fmaxf(fmaxf(v[q].x, v[q].y), fmaxf(v[q].z, v[q].w)));
        }
        float s = 0.0f;
#pragma unroll
        for (int q = 0; q < 6; q++)
            s += expf(v[q].x - m) + expf(v[q].y - m) + expf(v[q].z - m) + expf(v[q].w - m);
        float l = m + logf(s);
#pragma unroll
        for (int q = 0; q < 6; q++) {
            v[q].x -= l; v[q].y -= l; v[q].z -= l; v[q].w -= l;
            op4[q] = v[q];
        }
    }
}

// ---------------- fallback path (round-2 proven) ----------------

__global__ void hist_kernel(const int* __restrict__ dst, int* __restrict__ degi, int n_edges) {
    int i = blockIdx.x * blockDim.x + threadIdx.x;
    int base = i * 4;
    if (base + 3 < n_edges) {
        int4 d = *reinterpret_cast<const int4*>(dst + base);
        atomicAdd(&degi[d.x], 1);
        atomicAdd(&degi[d.y], 1);
        atomicAdd(&degi[d.z], 1);
        atomicAdd(&degi[d.w], 1);
    } else {
        for (int e = base; e < n_edges; e++) atomicAdd(&degi[dst[e]], 1);
    }
}

__global__ void __launch_bounds__(256) scan1_kernel(const int* __restrict__ in, int* __restrict__ out,
                                                    int* __restrict__ bsums, int n) {
    __shared__ int lds[256];
    int t = threadIdx.x;
    int base = blockIdx.x * 2048 + t * 8;
    int v[8];
    int s = 0;
#pragma unroll
    for (int i = 0; i < 8; i++) { v[i] = (base + i < n) ? in[base + i] : 0; s += v[i]; }
    lds[t] = s;
    __syncthreads();
    for (int off = 1; off < 256; off <<= 1) {
        int tv = (t >= off) ? lds[t - off] : 0;
        __syncthreads();
        lds[t] += tv;
        __syncthreads();
    }
    int excl = lds[t] - s;
    if (t == 255) bsums[blockIdx.x] = lds[255];
    int run = excl;
#pragma unroll
    for (int i = 0; i < 8; i++) {
        if (base + i < n) out[base + i] = run;
        run += v[i];
    }
}

__global__ void __launch_bounds__(256) scan2_kernel(int* __restrict__ bsums, int nb) {
    __shared__ int lds[256];
    int t = threadIdx.x;
    int v = (t < nb) ? bsums[t] : 0;
    lds[t] = v;
    __syncthreads();
    for (int off = 1; off < 256; off <<= 1) {
        int tv = (t >= off) ? lds[t - off] : 0;
        __syncthreads();
        lds[t] += tv;
        __syncthreads();
    }
    if (t < nb) bsums[t] = lds[t] - v;
}

__global__ void scan3_kernel(int* __restrict__ out, const int* __restrict__ bsums, int n) {
    int i = blockIdx.x * blockDim.x + threadIdx.x;
    if (i < n) out[i] += bsums[i >> 11];
}

__global__ void place_kernel(const int* __restrict__ src, const int* __restrict__ dst,
                             int* __restrict__ cursor, int* __restrict__ csr, int n_edges) {
    int e = blockIdx.x * blockDim.x + threadIdx.x;
    if (e < n_edges) {
        int d = dst[e];
        int pos = atomicAdd(&cursor[d], 1);
        csr[pos] = src[e];
    }
}

__global__ void __launch_bounds__(256) gather_mean26_kernel(
        const float* __restrict__ feat, const int* __restrict__ csr,
        const int* __restrict__ endoff, const int* __restrict__ degi,
        float* __restrict__ buf, int n_nodes) {
    int g = (blockIdx.x * 256 + threadIdx.x) >> 5;
    int lane = threadIdx.x & 31;
    if (g >= n_nodes) return;
    int end = endoff[g];
    int dg = degi[g];
    int start = end - dg;
    int c = lane < 26 ? lane : 0;
    float acc = 0.0f;
    int k = start;
    while (k < end) {
        int cnt = min(end - k, 32);
        int myid = (k + lane < end) ? csr[k + lane] : 0;
#pragma unroll 4
        for (int j = 0; j < cnt; j++) {
            int s = __shfl(myid, j, 32);
            acc += feat[(ll)s * 26 + c];
        }
        k += cnt;
    }
    float dinv = dg > 0 ? 1.0f / (float)dg : 0.0f;
    if (lane < 26) buf[(ll)g * 26 + lane] = acc * dinv;
}

__global__ void __launch_bounds__(256) node_mlp_fb_kernel(
        const float* __restrict__ feat, float* buf,
        const float* __restrict__ W1s, const float* __restrict__ W1n, const float* __restrict__ b1,
        const float* __restrict__ W2s, const float* __restrict__ W2n, const float* __restrict__ b2,
        float* __restrict__ outp, int n_nodes) {
    __shared__ float sW1s[26 * 40];
    __shared__ float sW1n[26 * 40];
    __shared__ float sW2s[40 * 24];
    __shared__ float sW2n[40 * 24];
    __shared__ float sb1[40];
    __shared__ float sb2[24];
    int t = threadIdx.x;
    for (int i = t; i < 26 * 40; i += 256) { sW1s[i] = W1s[i]; sW1n[i] = W1n[i]; }
    for (int i = t; i < 40 * 24; i += 256) { sW2s[i] = W2s[i]; sW2n[i] = W2n[i]; }
    if (t < 40) sb1[t] = b1[t];
    if (t < 24) sb2[t] = b2[t];
    __syncthreads();
    int n = blockIdx.x * 256 + t;
    if (n >= n_nodes) return;
    float h[40];
#pragma unroll
    for (int j = 0; j < 40; j++) h[j] = sb1[j];
    const float* fr = feat + (ll)n * 26;
    float* br = buf + (ll)n * 26;
#pragma unroll
    for (int k = 0; k < 26; k++) {
        float f = fr[k];
        float a = br[k];
#pragma unroll
        for (int j = 0; j < 40; j++) h[j] += f * sW1s[k * 40 + j] + a * sW1n[k * 40 + j];
    }
#pragma unroll
    for (int j = 0; j < 40; j++) h[j] = h[j] > 0.0f ? h[j] : 0.0f;
    float o[24], tt[24];
#pragma unroll
    for (int j = 0; j < 24; j++) { o[j] = sb2[j]; tt[j] = 0.0f; }
#pragma unroll
    for (int k = 0; k < 40; k++) {
        float hv = h[k];
#pragma unroll
        for (int j = 0; j < 24; j++) {
            o[j]  += hv * sW2s[k * 24 + j];
            tt[j] += hv * sW2n[k * 24 + j];
        }
    }
    float* op = outp + (ll)n * 24;
#pragma unroll
    for (int j = 0; j < 24; j++) op[j] = o[j];
#pragma unroll
    for (int j = 0; j < 24; j++) br[j] = tt[j];
}

__global__ void __launch_bounds__(256) gather_fin24_kernel(
        const float* __restrict__ buf, const int* __restrict__ csr,
        const int* __restrict__ endoff, const int* __restrict__ degi,
        float* __restrict__ outp, int n_nodes) {
    int g = (blockIdx.x * 256 + threadIdx.x) >> 5;
    int lane = threadIdx.x & 31;
    if (g >= n_nodes) return;
    int end = endoff[g];
    int dg = degi[g];
    int start = end - dg;
    int c = lane < 24 ? lane : 0;
    float acc = 0.0f;
    int k = start;
    while (k < end) {
        int cnt = min(end - k, 32);
        int myid = (k + lane < end) ? csr[k + lane] : 0;
#pragma unroll 4
        for (int j = 0; j < cnt; j++) {
            int s = __shfl(myid, j, 32);
            acc += buf[(ll)s * 26 + c];
        }
        k += cnt;
    }
    float dinv = dg > 0 ? 1.0f / (float)dg : 0.0f;
    float v = (lane < 24) ? outp[(ll)g * 24 + lane] + acc * dinv : -INFINITY;
    float m = v;
#pragma unroll
    for (int mask = 16; mask >= 1; mask >>= 1) m = fmaxf(m, __shfl_xor(m, mask, 32));
    float ex = (lane < 24) ? expf(v - m) : 0.0f;
    float ssum = ex;
#pragma unroll
    for (int mask = 16; mask >= 1; mask >>= 1) ssum += __shfl_xor(ssum, mask, 32);
    if (lane < 24) outp[(ll)g * 24 + lane] = v - m - logf(ssum);
}

// ---------------- launch ----------------

extern "C" void kernel_launch(void* const* d_in, const int* in_sizes, int n_in,
                              void* d_out, int out_size, void* d_ws, size_t ws_size,
                              hipStream_t stream) {
    const float* feat = (const float*)d_in[0];
    const int*   src  = (const int*)d_in[1];
    const int*   dst  = (const int*)d_in[2];
    const float* W1s  = (const float*)d_in[3];
    const float* W1n  = (const float*)d_in[4];
    const float* b1   = (const float*)d_in[5];
    const float* W2s  = (const float*)d_in[6];
    const float* W2n  = (const float*)d_in[7];
    const float* b2   = (const float*)d_in[8];

    int n_nodes = in_sizes[0] / 26;
    int n_edges = in_sizes[1];
    float* out = (float*)d_out;

    int NB = (n_nodes + BNODES - 1) >> BSHIFT;  // 391 for 200000

    // fast-path workspace (4B units, 16B-aligned blocks)
    size_t off = 0;
    auto alloc = [&off](size_t cnt) { size_t r = off; off += (cnt + 3) & ~(size_t)3; return r; };
    size_t o_bcnt   = alloc(512);
    size_t o_bstart = alloc(512);
    size_t o_bcur   = alloc(512);
    size_t o_ebuf   = alloc(n_edges);
    size_t o_featb  = alloc((size_t)n_nodes * 16);  // u16 x 32 per node
    size_t o_t2b    = alloc((size_t)n_nodes * 16);
    size_t o_mean   = alloc((size_t)n_nodes * 26);
    size_t o_dinv   = alloc(n_nodes);
    size_t need = off * 4;

    bool fast = (NB <= 512) && (n_nodes <= (1 << 18)) && (ws_size >= need);

    if (fast) {
        int* base    = (int*)d_ws;
        int* bcnt    = base + o_bcnt;
        int* bstart  = base + o_bstart;
        int* bcur    = base + o_bcur;
        u32* ebuf    = (u32*)(base + o_ebuf);
        u16* featb   = (u16*)(base + o_featb);
        u16* t2b     = (u16*)(base + o_t2b);
        float* meanb = (float*)(base + o_mean);
        float* dinvg = (float*)(base + o_dinv);

        hipMemsetAsync(bcnt, 0, sizeof(int) * 512, stream);

        int nchunks = (n_edges + BCHUNK - 1) / BCHUNK;
        bhist_kernel<<<nchunks, 512, 0, stream>>>(dst, bcnt, n_edges, NB);
        bscan_kernel<<<1, 512, 0, stream>>>(bcnt, bstart, bcur, NB);
        {
            int total = n_nodes * 32;
            featb_kernel<<<(total + 255) / 256, 256, 0, stream>>>(feat, featb, total);
        }
        bin_kernel<<<nchunks, 512, 0, stream>>>(src, dst, bcur, ebuf, n_edges, NB);

        agg1_kernel<<<NB, 512, 0, stream>>>(featb, ebuf, bstart, bcur, meanb, dinvg, n_nodes);

        node_mlp_kernel<<<(n_nodes + 255) / 256, 256, 0, stream>>>(
            feat, meanb, W1s, W1n, b1, W2s, W2n, b2, out, t2b, n_nodes);

        agg2_kernel<<<NB, 512, 0, stream>>>(t2b, ebuf, bstart, bcur, dinvg, out, n_nodes);
    } else {
        // round-2 proven fallback
        int* degi  = (int*)d_ws;
        int* offs  = degi + n_nodes;
        int* bsums = offs + n_nodes;
        int* csr   = bsums + 256;
        float* buf = (float*)(csr + n_edges);

        hipMemsetAsync(degi, 0, sizeof(int) * (size_t)n_nodes, stream);
        {
            int work = (n_edges + 3) / 4;
            hist_kernel<<<(work + 255) / 256, 256, 0, stream>>>(dst, degi, n_edges);
        }
        int scan_blocks = (n_nodes + 2047) / 2048;
        scan1_kernel<<<scan_blocks, 256, 0, stream>>>(degi, offs, bsums, n_nodes);
        scan2_kernel<<<1, 256, 0, stream>>>(bsums, scan_blocks);
        scan3_kernel<<<(n_nodes + 255) / 256, 256, 0, stream>>>(offs, bsums, n_nodes);

        place_kernel<<<(n_edges + 255) / 256, 256, 0, stream>>>(src, dst, offs, csr, n_edges);

        int gather_blocks = (n_nodes * 32 + 255) / 256;
        gather_mean26_kernel<<<gather_blocks, 256, 0, stream>>>(feat, csr, offs, degi, buf, n_nodes);

        node_mlp_fb_kernel<<<(n_nodes + 255) / 256, 256, 0, stream>>>(
            feat, buf, W1s, W1n, b1, W2s, W2n, b2, out, n_nodes);

        gather_fin24_kernel<<<gather_blocks, 256, 0, stream>>>(buf, csr, offs, degi, out, n_nodes);
    }
}

// Round 5
// 422.583 us; speedup vs baseline: 5.7149x; 5.7149x over previous
//
#include <hip/hip_runtime.h>
#include <math.h>

// GraphSAGE-mean 2-layer. Bucket bin -> per-bucket counting-sort CSR build
// (scattered writes confined to L2-resident 64KB ranges) -> bf16-table gathers
// (one 64B line per neighbor row) -> fused MLP -> fused finalize.
//
// Fast path:
//   bhist (edges per 512-node bucket) -> bscan -> featb (f32->bf16 rows of 32) ->
//   bin (LDS multi-split into bucket-major ebuf, packs (dst_local<<18)|src) ->
//   place3 (per-bucket LDS counting sort -> csr, degi, endoff) ->
//   gatherb<0> (mean of featb rows -> meanb f32 stride 32) ->
//   node_mlp (h1 = relu(feat@W1s + mean@W1n + b1); out = h1@W2s + b2; t2b = bf16(h1@W2n), pads zeroed) ->
//   gatherb<1> (mean of t2b rows + fused log_softmax into out).
// Layer-2 trick: aggregate h1@W2_neigh (24 dims) instead of h1 (40) — mean commutes with linear.
// Aliases: meanb reuses ebuf (dead after place3); t2b reuses featb (dead after gatherb<0>).

typedef long long ll;
typedef unsigned int u32;
typedef unsigned short u16;

__device__ inline u16 f2bf(float f) {
    u32 u = __builtin_bit_cast(u32, f);
    u32 r = (u + 0x7FFFu + ((u >> 16) & 1u)) >> 16;
    return (u16)r;
}
__device__ inline float bf2f(u16 h) {
    u32 u = ((u32)h) << 16;
    return __builtin_bit_cast(float, u);
}

#define BSHIFT 9
#define BNODES 512
#define BCHUNK 8192

// ---------------- bucket histogram + scan ----------------

__global__ void __launch_bounds__(512) bhist_kernel(const int* __restrict__ dst,
                                                    int* __restrict__ bcnt, int n_edges, int nb) {
    __shared__ int cnt[512];
    int t = threadIdx.x;
    cnt[t] = 0;
    __syncthreads();
    int base = blockIdx.x * BCHUNK;
#pragma unroll
    for (int j = 0; j < BCHUNK / 512; j++) {
        int i = base + t + j * 512;
        if (i < n_edges) atomicAdd(&cnt[dst[i] >> BSHIFT], 1);
    }
    __syncthreads();
    if (t < nb && cnt[t]) atomicAdd(&bcnt[t], cnt[t]);
}

__global__ void __launch_bounds__(512) bscan_kernel(const int* __restrict__ bcnt,
                                                    int* __restrict__ bstart, int* __restrict__ bcur, int nb) {
    __shared__ int lds[512];
    int t = threadIdx.x;
    int v = (t < nb) ? bcnt[t] : 0;
    lds[t] = v;
    __syncthreads();
    for (int off = 1; off < 512; off <<= 1) {
        int tv = (t >= off) ? lds[t - off] : 0;
        __syncthreads();
        lds[t] += tv;
        __syncthreads();
    }
    int excl = lds[t] - v;
    if (t < nb) { bstart[t] = excl; bcur[t] = excl; }
}

// ---------------- feat -> bf16 padded table ----------------

__global__ void featb_kernel(const float* __restrict__ feat, u16* __restrict__ featb, int total) {
    int i = blockIdx.x * 256 + threadIdx.x;
    if (i >= total) return;
    int n = i >> 5, c = i & 31;
    featb[i] = (c < 26) ? f2bf(feat[n * 26 + c]) : (u16)0;
}

// ---------------- bin: LDS multi-split into NB buckets (bucket-major ebuf) ----------------

__global__ void __launch_bounds__(512) bin_kernel(const int* __restrict__ src, const int* __restrict__ dst,
                                                  int* __restrict__ bcur, u32* __restrict__ ebuf,
                                                  int n_edges, int nb) {
    __shared__ int cnt[512];    // counts, then running cursors
    __shared__ int sc[512];     // scan workspace
    __shared__ int loff[512];   // exclusive offsets (stable)
    __shared__ int gbase[512];
    __shared__ u32 stage[BCHUNK];
    int t = threadIdx.x;
    int base = blockIdx.x * BCHUNK;
    cnt[t] = 0;
    __syncthreads();
#pragma unroll
    for (int j = 0; j < BCHUNK / 512; j++) {
        int i = base + t + j * 512;
        if (i < n_edges) atomicAdd(&cnt[dst[i] >> BSHIFT], 1);
    }
    __syncthreads();
    int v = cnt[t];
    sc[t] = v;
    __syncthreads();
    for (int off = 1; off < 512; off <<= 1) {
        int tv = (t >= off) ? sc[t - off] : 0;
        __syncthreads();
        sc[t] += tv;
        __syncthreads();
    }
    int excl = sc[t] - v;
    loff[t] = excl;
    if (t < nb && v) gbase[t] = atomicAdd(&bcur[t], v);
    __syncthreads();
    cnt[t] = excl;
    __syncthreads();
#pragma unroll
    for (int j = 0; j < BCHUNK / 512; j++) {
        int i = base + t + j * 512;
        if (i < n_edges) {
            int d = dst[i];
            int b = d >> BSHIFT;
            u32 u = ((u32)(d & (BNODES - 1)) << 18) | (u32)src[i];
            int p = atomicAdd(&cnt[b], 1);
            stage[p] = u;
        }
    }
    __syncthreads();
    int total = min(n_edges - base, BCHUNK);
    for (int i = t; i < total; i += 512) {
        int lo = 0, hi = nb - 1;
        while (lo < hi) { int mid = (lo + hi + 1) >> 1; if (i >= loff[mid]) lo = mid; else hi = mid - 1; }
        ebuf[gbase[lo] + (i - loff[lo])] = stage[i];
    }
}

// ---------------- place3: per-bucket counting sort -> csr + degi + endoff ----------------

__global__ void __launch_bounds__(512) place3_kernel(const u32* __restrict__ ebuf,
                                                     const int* __restrict__ bstart, const int* __restrict__ bend,
                                                     int* __restrict__ csr,
                                                     int* __restrict__ degi, int* __restrict__ endoff,
                                                     int n_nodes) {
    __shared__ int cnt[512];
    __shared__ int sc[512];
    __shared__ int cur[512];
    int t = threadIdx.x;
    int b = blockIdx.x;
    int base = bstart[b];
    int endb = bend[b];
    cnt[t] = 0;
    __syncthreads();
    // pass 1: per-node counts
    for (int i = base + t; i < endb; i += 512) {
        atomicAdd(&cnt[ebuf[i] >> 18], 1);
    }
    __syncthreads();
    int v = cnt[t];
    sc[t] = v;
    __syncthreads();
    for (int off = 1; off < 512; off <<= 1) {
        int tv = (t >= off) ? sc[t - off] : 0;
        __syncthreads();
        sc[t] += tv;
        __syncthreads();
    }
    int excl = sc[t] - v;
    cur[t] = excl;
    int node0 = b << BSHIFT;
    if (node0 + t < n_nodes) {
        degi[node0 + t] = v;
        endoff[node0 + t] = base + excl + v;
    }
    __syncthreads();
    // pass 2: scatter src ids into the bucket's contiguous csr range (L2-resident)
    for (int i = base + t; i < endb; i += 512) {
        u32 u = ebuf[i];
        int dl = (int)(u >> 18);
        int p = atomicAdd(&cur[dl], 1);
        csr[base + p] = (int)(u & 0x3FFFFu);
    }
}

// ---------------- gathers on bf16 tables (rows = 32 bf16 = 64B) ----------------

// One node per 32-lane group. lane = slot*8+q: slot in [0,4) = neighbor, q in [0,8) = 8B chunk.
// FIN=0: meanb[g*32+..] = mean (f32). FIN=1: out = log_softmax(out + mean) over 24 cols.
template<int FIN>
__global__ void __launch_bounds__(256) gatherb_kernel(
        const u16* __restrict__ table, const int* __restrict__ csr,
        const int* __restrict__ endoff, const int* __restrict__ degi,
        float* __restrict__ meanb, float* __restrict__ outp, int n_nodes) {
    int g = (blockIdx.x * 256 + threadIdx.x) >> 5;
    if (g >= n_nodes) return;
    int lane = threadIdx.x & 31;
    int slot = lane >> 3;
    int q = lane & 7;
    int end = endoff[g];
    int dg = degi[g];
    int start = end - dg;
    float4 acc = make_float4(0.f, 0.f, 0.f, 0.f);
    for (int k = start; k < end; k += 32) {
        int cnt = min(end - k, 32);
        int myid = (lane < cnt) ? csr[k + lane] : 0;
#pragma unroll
        for (int it = 0; it < 8; it++) {
            if ((it << 2) >= cnt) break;
            int nidx = (it << 2) + slot;
            int s = __shfl(myid, nidx, 32);
            if (nidx < cnt) {
                ushort4 v = *reinterpret_cast<const ushort4*>(table + ((ll)s << 5) + (q << 2));
                acc.x += bf2f(v.x); acc.y += bf2f(v.y); acc.z += bf2f(v.z); acc.w += bf2f(v.w);
            }
        }
    }
#pragma unroll
    for (int m = 8; m <= 16; m <<= 1) {
        acc.x += __shfl_xor(acc.x, m, 32);
        acc.y += __shfl_xor(acc.y, m, 32);
        acc.z += __shfl_xor(acc.z, m, 32);
        acc.w += __shfl_xor(acc.w, m, 32);
    }
    float dinv = dg > 0 ? 1.0f / (float)dg : 0.0f;
    if (FIN == 0) {
        if (lane < 8) {
            float4 r = make_float4(acc.x * dinv, acc.y * dinv, acc.z * dinv, acc.w * dinv);
            *(reinterpret_cast<float4*>(meanb + ((ll)g << 5)) + q) = r;
        }
    } else {
        if (lane < 8) {
            float4 v = make_float4(0.f, 0.f, 0.f, 0.f);
            if (q < 6) {
                v = *(reinterpret_cast<float4*>(outp + (ll)g * 24) + q);
                v.x += acc.x * dinv; v.y += acc.y * dinv; v.z += acc.z * dinv; v.w += acc.w * dinv;
            }
            float vm = (q < 6) ? fmaxf(fmaxf(v.x, v.y), fmaxf(v.z, v.w)) : -INFINITY;
#pragma unroll
            for (int m = 1; m <= 4; m <<= 1) vm = fmaxf(vm, __shfl_xor(vm, m, 32));
            float es = (q < 6) ? (expf(v.x - vm) + expf(v.y - vm) + expf(v.z - vm) + expf(v.w - vm)) : 0.0f;
#pragma unroll
            for (int m = 1; m <= 4; m <<= 1) es += __shfl_xor(es, m, 32);
            if (q < 6) {
                float l = vm + logf(es);
                v.x -= l; v.y -= l; v.z -= l; v.w -= l;
                *(reinterpret_cast<float4*>(outp + (ll)g * 24) + q) = v;
            }
        }
    }
}

// ---------------- node MLP ----------------

__global__ void __launch_bounds__(256) node_mlp_kernel(
        const float* __restrict__ feat, const float* __restrict__ meanb,
        const float* __restrict__ W1s, const float* __restrict__ W1n, const float* __restrict__ b1,
        const float* __restrict__ W2s, const float* __restrict__ W2n, const float* __restrict__ b2,
        float* __restrict__ outp, u16* __restrict__ t2b, int n_nodes) {
    __shared__ float sW1s[26 * 40];
    __shared__ float sW1n[26 * 40];
    __shared__ float sW2s[40 * 24];
    __shared__ float sW2n[40 * 24];
    __shared__ float sb1[40];
    __shared__ float sb2[24];
    int t = threadIdx.x;
    for (int i = t; i < 26 * 40; i += 256) { sW1s[i] = W1s[i]; sW1n[i] = W1n[i]; }
    for (int i = t; i < 40 * 24; i += 256) { sW2s[i] = W2s[i]; sW2n[i] = W2n[i]; }
    if (t < 40) sb1[t] = b1[t];
    if (t < 24) sb2[t] = b2[t];
    __syncthreads();

    int n = blockIdx.x * 256 + t;
    if (n >= n_nodes) return;

    float h[40];
#pragma unroll
    for (int j = 0; j < 40; j++) h[j] = sb1[j];

    const float* fr = feat + (ll)n * 26;
    const float* br = meanb + ((ll)n << 5);
#pragma unroll
    for (int k = 0; k < 26; k++) {
        float f = fr[k];
        float a = br[k];
#pragma unroll
        for (int j = 0; j < 40; j++) h[j] += f * sW1s[k * 40 + j] + a * sW1n[k * 40 + j];
    }
#pragma unroll
    for (int j = 0; j < 40; j++) h[j] = h[j] > 0.0f ? h[j] : 0.0f;

    float o[24], tt[24];
#pragma unroll
    for (int j = 0; j < 24; j++) { o[j] = sb2[j]; tt[j] = 0.0f; }
#pragma unroll
    for (int k = 0; k < 40; k++) {
        float hv = h[k];
#pragma unroll
        for (int j = 0; j < 24; j++) {
            o[j]  += hv * sW2s[k * 24 + j];
            tt[j] += hv * sW2n[k * 24 + j];
        }
    }
    float* op = outp + (ll)n * 24;
#pragma unroll
    for (int j = 0; j < 24; j++) op[j] = o[j];
    u16* tp = t2b + ((ll)n << 5);
#pragma unroll
    for (int j = 0; j < 24; j++) tp[j] = f2bf(tt[j]);
#pragma unroll
    for (int j = 24; j < 32; j++) tp[j] = (u16)0;  // pads must be zero: gather reads full 64B rows
}

// ---------------- fallback path (round-2 proven) ----------------

__global__ void hist_kernel(const int* __restrict__ dst, int* __restrict__ degi, int n_edges) {
    int i = blockIdx.x * blockDim.x + threadIdx.x;
    int base = i * 4;
    if (base + 3 < n_edges) {
        int4 d = *reinterpret_cast<const int4*>(dst + base);
        atomicAdd(&degi[d.x], 1);
        atomicAdd(&degi[d.y], 1);
        atomicAdd(&degi[d.z], 1);
        atomicAdd(&degi[d.w], 1);
    } else {
        for (int e = base; e < n_edges; e++) atomicAdd(&degi[dst[e]], 1);
    }
}

__global__ void __launch_bounds__(256) scan1_kernel(const int* __restrict__ in, int* __restrict__ out,
                                                    int* __restrict__ bsums, int n) {
    __shared__ int lds[256];
    int t = threadIdx.x;
    int base = blockIdx.x * 2048 + t * 8;
    int v[8];
    int s = 0;
#pragma unroll
    for (int i = 0; i < 8; i++) { v[i] = (base + i < n) ? in[base + i] : 0; s += v[i]; }
    lds[t] = s;
    __syncthreads();
    for (int off = 1; off < 256; off <<= 1) {
        int tv = (t >= off) ? lds[t - off] : 0;
        __syncthreads();
        lds[t] += tv;
        __syncthreads();
    }
    int excl = lds[t] - s;
    if (t == 255) bsums[blockIdx.x] = lds[255];
    int run = excl;
#pragma unroll
    for (int i = 0; i < 8; i++) {
        if (base + i < n) out[base + i] = run;
        run += v[i];
    }
}

__global__ void __launch_bounds__(256) scan2_kernel(int* __restrict__ bsums, int nb) {
    __shared__ int lds[256];
    int t = threadIdx.x;
    int v = (t < nb) ? bsums[t] : 0;
    lds[t] = v;
    __syncthreads();
    for (int off = 1; off < 256; off <<= 1) {
        int tv = (t >= off) ? lds[t - off] : 0;
        __syncthreads();
        lds[t] += tv;
        __syncthreads();
    }
    if (t < nb) bsums[t] = lds[t] - v;
}

__global__ void scan3_kernel(int* __restrict__ out, const int* __restrict__ bsums, int n) {
    int i = blockIdx.x * blockDim.x + threadIdx.x;
    if (i < n) out[i] += bsums[i >> 11];
}

__global__ void place_kernel(const int* __restrict__ src, const int* __restrict__ dst,
                             int* __restrict__ cursor, int* __restrict__ csr, int n_edges) {
    int e = blockIdx.x * blockDim.x + threadIdx.x;
    if (e < n_edges) {
        int d = dst[e];
        int pos = atomicAdd(&cursor[d], 1);
        csr[pos] = src[e];
    }
}

__global__ void __launch_bounds__(256) gather_mean26_kernel(
        const float* __restrict__ feat, const int* __restrict__ csr,
        const int* __restrict__ endoff, const int* __restrict__ degi,
        float* __restrict__ buf, int n_nodes) {
    int g = (blockIdx.x * 256 + threadIdx.x) >> 5;
    int lane = threadIdx.x & 31;
    if (g >= n_nodes) return;
    int end = endoff[g];
    int dg = degi[g];
    int start = end - dg;
    int c = lane < 26 ? lane : 0;
    float acc = 0.0f;
    int k = start;
    while (k < end) {
        int cnt = min(end - k, 32);
        int myid = (k + lane < end) ? csr[k + lane] : 0;
#pragma unroll 4
        for (int j = 0; j < cnt; j++) {
            int s = __shfl(myid, j, 32);
            acc += feat[(ll)s * 26 + c];
        }
        k += cnt;
    }
    float dinv = dg > 0 ? 1.0f / (float)dg : 0.0f;
    if (lane < 26) buf[(ll)g * 26 + lane] = acc * dinv;
}

__global__ void __launch_bounds__(256) node_mlp_fb_kernel(
        const float* __restrict__ feat, float* buf,
        const float* __restrict__ W1s, const float* __restrict__ W1n, const float* __restrict__ b1,
        const float* __restrict__ W2s, const float* __restrict__ W2n, const float* __restrict__ b2,
        float* __restrict__ outp, int n_nodes) {
    __shared__ float sW1s[26 * 40];
    __shared__ float sW1n[26 * 40];
    __shared__ float sW2s[40 * 24];
    __shared__ float sW2n[40 * 24];
    __shared__ float sb1[40];
    __shared__ float sb2[24];
    int t = threadIdx.x;
    for (int i = t; i < 26 * 40; i += 256) { sW1s[i] = W1s[i]; sW1n[i] = W1n[i]; }
    for (int i = t; i < 40 * 24; i += 256) { sW2s[i] = W2s[i]; sW2n[i] = W2n[i]; }
    if (t < 40) sb1[t] = b1[t];
    if (t < 24) sb2[t] = b2[t];
    __syncthreads();
    int n = blockIdx.x * 256 + t;
    if (n >= n_nodes) return;
    float h[40];
#pragma unroll
    for (int j = 0; j < 40; j++) h[j] = sb1[j];
    const float* fr = feat + (ll)n * 26;
    float* br = buf + (ll)n * 26;
#pragma unroll
    for (int k = 0; k < 26; k++) {
        float f = fr[k];
        float a = br[k];
#pragma unroll
        for (int j = 0; j < 40; j++) h[j] += f * sW1s[k * 40 + j] + a * sW1n[k * 40 + j];
    }
#pragma unroll
    for (int j = 0; j < 40; j++) h[j] = h[j] > 0.0f ? h[j] : 0.0f;
    float o[24], tt[24];
#pragma unroll
    for (int j = 0; j < 24; j++) { o[j] = sb2[j]; tt[j] = 0.0f; }
#pragma unroll
    for (int k = 0; k < 40; k++) {
        float hv = h[k];
#pragma unroll
        for (int j = 0; j < 24; j++) {
            o[j]  += hv * sW2s[k * 24 + j];
            tt[j] += hv * sW2n[k * 24 + j];
        }
    }
    float* op = outp + (ll)n * 24;
#pragma unroll
    for (int j = 0; j < 24; j++) op[j] = o[j];
#pragma unroll
    for (int j = 0; j < 24; j++) br[j] = tt[j];
}

__global__ void __launch_bounds__(256) gather_fin24_kernel(
        const float* __restrict__ buf, const int* __restrict__ csr,
        const int* __restrict__ endoff, const int* __restrict__ degi,
        float* __restrict__ outp, int n_nodes) {
    int g = (blockIdx.x * 256 + threadIdx.x) >> 5;
    int lane = threadIdx.x & 31;
    if (g >= n_nodes) return;
    int end = endoff[g];
    int dg = degi[g];
    int start = end - dg;
    int c = lane < 24 ? lane : 0;
    float acc = 0.0f;
    int k = start;
    while (k < end) {
        int cnt = min(end - k, 32);
        int myid = (k + lane < end) ? csr[k + lane] : 0;
#pragma unroll 4
        for (int j = 0; j < cnt; j++) {
            int s = __shfl(myid, j, 32);
            acc += buf[(ll)s * 26 + c];
        }
        k += cnt;
    }
    float dinv = dg > 0 ? 1.0f / (float)dg : 0.0f;
    float v = (lane < 24) ? outp[(ll)g * 24 + lane] + acc * dinv : -INFINITY;
    float m = v;
#pragma unroll
    for (int mask = 16; mask >= 1; mask >>= 1) m = fmaxf(m, __shfl_xor(m, mask, 32));
    float ex = (lane < 24) ? expf(v - m) : 0.0f;
    float ssum = ex;
#pragma unroll
    for (int mask = 16; mask >= 1; mask >>= 1) ssum += __shfl_xor(ssum, mask, 32);
    if (lane < 24) outp[(ll)g * 24 + lane] = v - m - logf(ssum);
}

// ---------------- launch ----------------

extern "C" void kernel_launch(void* const* d_in, const int* in_sizes, int n_in,
                              void* d_out, int out_size, void* d_ws, size_t ws_size,
                              hipStream_t stream) {
    const float* feat = (const float*)d_in[0];
    const int*   src  = (const int*)d_in[1];
    const int*   dst  = (const int*)d_in[2];
    const float* W1s  = (const float*)d_in[3];
    const float* W1n  = (const float*)d_in[4];
    const float* b1   = (const float*)d_in[5];
    const float* W2s  = (const float*)d_in[6];
    const float* W2n  = (const float*)d_in[7];
    const float* b2   = (const float*)d_in[8];

    int n_nodes = in_sizes[0] / 26;
    int n_edges = in_sizes[1];
    float* out = (float*)d_out;

    int NB = (n_nodes + BNODES - 1) >> BSHIFT;  // 391 for 200000

    // fast-path workspace (4B units, 16B-aligned blocks)
    size_t off = 0;
    auto alloc = [&off](size_t cnt) { size_t r = off; off += (cnt + 3) & ~(size_t)3; return r; };
    size_t o_bcnt   = alloc(512);
    size_t o_bstart = alloc(512);
    size_t o_bcur   = alloc(512);
    size_t o_ebuf   = alloc((size_t)n_edges < (size_t)n_nodes * 32 ? (size_t)n_nodes * 32
                                                                   : (size_t)n_edges);  // aliased as meanb f32 x32
    size_t o_csr    = alloc(n_edges);
    size_t o_featb  = alloc((size_t)n_nodes * 16);  // u16 x 32 per node; aliased as t2b
    size_t o_degi   = alloc(n_nodes);
    size_t o_endo   = alloc(n_nodes);
    size_t need = off * 4;

    bool fast = (NB <= 512) && (n_nodes <= (1 << 18)) && (ws_size >= need);

    if (fast) {
        int* base    = (int*)d_ws;
        int* bcnt    = base + o_bcnt;
        int* bstart  = base + o_bstart;
        int* bcur    = base + o_bcur;
        u32* ebuf    = (u32*)(base + o_ebuf);
        int* csr     = base + o_csr;
        u16* featb   = (u16*)(base + o_featb);
        u16* t2b     = featb;                    // alias: featb dead after gatherb<0>
        float* meanb = (float*)ebuf;             // alias: ebuf dead after place3
        int* degi    = base + o_degi;
        int* endoff  = base + o_endo;

        hipMemsetAsync(bcnt, 0, sizeof(int) * 512, stream);

        int nchunks = (n_edges + BCHUNK - 1) / BCHUNK;
        bhist_kernel<<<nchunks, 512, 0, stream>>>(dst, bcnt, n_edges, NB);
        bscan_kernel<<<1, 512, 0, stream>>>(bcnt, bstart, bcur, NB);
        {
            int total = n_nodes * 32;
            featb_kernel<<<(total + 255) / 256, 256, 0, stream>>>(feat, featb, total);
        }
        bin_kernel<<<nchunks, 512, 0, stream>>>(src, dst, bcur, ebuf, n_edges, NB);

        place3_kernel<<<NB, 512, 0, stream>>>(ebuf, bstart, bcur, csr, degi, endoff, n_nodes);

        int gather_blocks = (n_nodes * 32 + 255) / 256;
        gatherb_kernel<0><<<gather_blocks, 256, 0, stream>>>(featb, csr, endoff, degi, meanb, nullptr, n_nodes);

        node_mlp_kernel<<<(n_nodes + 255) / 256, 256, 0, stream>>>(
            feat, meanb, W1s, W1n, b1, W2s, W2n, b2, out, t2b, n_nodes);

        gatherb_kernel<1><<<gather_blocks, 256, 0, stream>>>(t2b, csr, endoff, degi, nullptr, out, n_nodes);
    } else {
        // round-2 proven fallback
        int* degi  = (int*)d_ws;
        int* offs  = degi + n_nodes;
        int* bsums = offs + n_nodes;
        int* csr   = bsums + 256;
        float* buf = (float*)(csr + n_edges);

        hipMemsetAsync(degi, 0, sizeof(int) * (size_t)n_nodes, stream);
        {
            int work = (n_edges + 3) / 4;
            hist_kernel<<<(work + 255) / 256, 256, 0, stream>>>(dst, degi, n_edges);
        }
        int scan_blocks = (n_nodes + 2047) / 2048;
        scan1_kernel<<<scan_blocks, 256, 0, stream>>>(degi, offs, bsums, n_nodes);
        scan2_kernel<<<1, 256, 0, stream>>>(bsums, scan_blocks);
        scan3_kernel<<<(n_nodes + 255) / 256, 256, 0, stream>>>(offs, bsums, n_nodes);

        place_kernel<<<(n_edges + 255) / 256, 256, 0, stream>>>(src, dst, offs, csr, n_edges);

        int gather_blocks = (n_nodes * 32 + 255) / 256;
        gather_mean26_kernel<<<gather_blocks, 256, 0, stream>>>(feat, csr, offs, degi, buf, n_nodes);

        node_mlp_fb_kernel<<<(n_nodes + 255) / 256, 256, 0, stream>>>(
            feat, buf, W1s, W1n, b1, W2s, W2n, b2, out, n_nodes);

        gather_fin24_kernel<<<gather_blocks, 256, 0, stream>>>(buf, csr, offs, degi, out, n_nodes);
    }
}

// Round 6
// 411.436 us; speedup vs baseline: 5.8697x; 1.0271x over previous
//
#include <hip/hip_runtime.h>
#include <math.h>

// GraphSAGE-mean 2-layer. Bucket bin -> per-bucket counting-sort CSR build
// (scattered writes confined to L2-resident 64KB ranges) -> bf16-table gathers
// (one 64B line per neighbor row) -> fused MLP -> fused finalize.
//
// Fast path:
//   bhist_featb (edges per 512-node bucket; tail blocks convert feat f32->bf16 rows of 32) ->
//   bscan -> bin (LDS multi-split into bucket-major ebuf, dst register-cached, packs (dst_local<<18)|src) ->
//   place3 (per-bucket LDS counting sort -> csr, degi, endoff) ->
//   gatherb<0> (mean of featb rows -> meanb bf16 stride 32) ->
//   node_mlp (h1 = relu(feat@W1s + mean@W1n + b1); out = h1@W2s + b2; t2b = bf16(h1@W2n), pads zeroed) ->
//   gatherb<1> (mean of t2b rows + fused log_softmax into out).
// Layer-2 trick: aggregate h1@W2_neigh (24 dims) instead of h1 (40) — mean commutes with linear.
// Aliases: meanb reuses ebuf (dead after place3); t2b reuses featb (dead after gatherb<0>).

typedef long long ll;
typedef unsigned int u32;
typedef unsigned short u16;

__device__ inline u16 f2bf(float f) {
    u32 u = __builtin_bit_cast(u32, f);
    u32 r = (u + 0x7FFFu + ((u >> 16) & 1u)) >> 16;
    return (u16)r;
}
__device__ inline float bf2f(u16 h) {
    u32 u = ((u32)h) << 16;
    return __builtin_bit_cast(float, u);
}

#define BSHIFT 9
#define BNODES 512
#define BCHUNK 8192

// ---------------- fused bucket histogram + feat->bf16 table ----------------

__global__ void __launch_bounds__(512) bhist_featb_kernel(
        const int* __restrict__ dst, int* __restrict__ bcnt, int n_edges, int nb, int nchunks,
        const float* __restrict__ feat, u16* __restrict__ featb, int fb_total) {
    int t = threadIdx.x;
    if ((int)blockIdx.x < nchunks) {
        __shared__ int cnt[512];
        cnt[t] = 0;
        __syncthreads();
        int base = blockIdx.x * BCHUNK;
#pragma unroll
        for (int j = 0; j < BCHUNK / 512; j++) {
            int i = base + t + j * 512;
            if (i < n_edges) atomicAdd(&cnt[dst[i] >> BSHIFT], 1);
        }
        __syncthreads();
        if (t < nb && cnt[t]) atomicAdd(&bcnt[t], cnt[t]);
    } else {
        int i = ((int)blockIdx.x - nchunks) * 512 + t;
        if (i < fb_total) {
            int n = i >> 5, c = i & 31;
            featb[i] = (c < 26) ? f2bf(feat[n * 26 + c]) : (u16)0;
        }
    }
}

__global__ void __launch_bounds__(512) bscan_kernel(const int* __restrict__ bcnt,
                                                    int* __restrict__ bstart, int* __restrict__ bcur, int nb) {
    __shared__ int lds[512];
    int t = threadIdx.x;
    int v = (t < nb) ? bcnt[t] : 0;
    lds[t] = v;
    __syncthreads();
    for (int off = 1; off < 512; off <<= 1) {
        int tv = (t >= off) ? lds[t - off] : 0;
        __syncthreads();
        lds[t] += tv;
        __syncthreads();
    }
    int excl = lds[t] - v;
    if (t < nb) { bstart[t] = excl; bcur[t] = excl; }
}

// ---------------- bin: LDS multi-split into NB buckets (bucket-major ebuf) ----------------

__global__ void __launch_bounds__(512) bin_kernel(const int* __restrict__ src, const int* __restrict__ dst,
                                                  int* __restrict__ bcur, u32* __restrict__ ebuf,
                                                  int n_edges, int nb) {
    __shared__ int cnt[512];    // counts, then running cursors
    __shared__ int sc[512];     // scan workspace
    __shared__ int loff[512];   // exclusive offsets (stable)
    __shared__ int gbase[512];
    __shared__ u32 stage[BCHUNK];
    int t = threadIdx.x;
    int base = blockIdx.x * BCHUNK;
    cnt[t] = 0;
    __syncthreads();
    int dv[BCHUNK / 512];  // register-cached dst values (one global read instead of two)
#pragma unroll
    for (int j = 0; j < BCHUNK / 512; j++) {
        int i = base + t + j * 512;
        dv[j] = (i < n_edges) ? dst[i] : -1;
        if (dv[j] >= 0) atomicAdd(&cnt[dv[j] >> BSHIFT], 1);
    }
    __syncthreads();
    int v = cnt[t];
    sc[t] = v;
    __syncthreads();
    for (int off = 1; off < 512; off <<= 1) {
        int tv = (t >= off) ? sc[t - off] : 0;
        __syncthreads();
        sc[t] += tv;
        __syncthreads();
    }
    int excl = sc[t] - v;
    loff[t] = excl;
    if (t < nb && v) gbase[t] = atomicAdd(&bcur[t], v);
    __syncthreads();
    cnt[t] = excl;
    __syncthreads();
#pragma unroll
    for (int j = 0; j < BCHUNK / 512; j++) {
        int i = base + t + j * 512;
        if (dv[j] >= 0) {
            int d = dv[j];
            int b = d >> BSHIFT;
            u32 u = ((u32)(d & (BNODES - 1)) << 18) | (u32)src[i];
            int p = atomicAdd(&cnt[b], 1);
            stage[p] = u;
        }
    }
    __syncthreads();
    int total = min(n_edges - base, BCHUNK);
    for (int i = t; i < total; i += 512) {
        int lo = 0, hi = nb - 1;
        while (lo < hi) { int mid = (lo + hi + 1) >> 1; if (i >= loff[mid]) lo = mid; else hi = mid - 1; }
        ebuf[gbase[lo] + (i - loff[lo])] = stage[i];
    }
}

// ---------------- place3: per-bucket counting sort -> csr + degi + endoff ----------------

__global__ void __launch_bounds__(512) place3_kernel(const u32* __restrict__ ebuf,
                                                     const int* __restrict__ bstart, const int* __restrict__ bend,
                                                     int* __restrict__ csr,
                                                     int* __restrict__ degi, int* __restrict__ endoff,
                                                     int n_nodes) {
    __shared__ int cnt[512];
    __shared__ int sc[512];
    __shared__ int cur[512];
    int t = threadIdx.x;
    int b = blockIdx.x;
    int base = bstart[b];
    int endb = bend[b];
    cnt[t] = 0;
    __syncthreads();
    for (int i = base + t; i < endb; i += 512) {
        atomicAdd(&cnt[ebuf[i] >> 18], 1);
    }
    __syncthreads();
    int v = cnt[t];
    sc[t] = v;
    __syncthreads();
    for (int off = 1; off < 512; off <<= 1) {
        int tv = (t >= off) ? sc[t - off] : 0;
        __syncthreads();
        sc[t] += tv;
        __syncthreads();
    }
    int excl = sc[t] - v;
    cur[t] = excl;
    int node0 = b << BSHIFT;
    if (node0 + t < n_nodes) {
        degi[node0 + t] = v;
        endoff[node0 + t] = base + excl + v;
    }
    __syncthreads();
    for (int i = base + t; i < endb; i += 512) {
        u32 u = ebuf[i];
        int dl = (int)(u >> 18);
        int p = atomicAdd(&cur[dl], 1);
        csr[base + p] = (int)(u & 0x3FFFFu);
    }
}

// ---------------- gathers on bf16 tables (rows = 32 bf16 = 64B) ----------------

// One node per 32-lane group. lane = slot*8+q: slot in [0,4) = neighbor, q in [0,8) = 8B chunk.
// FIN=0: meanb (bf16 rows of 32) = mean. FIN=1: out = log_softmax(out + mean) over 24 cols.
template<int FIN>
__global__ void __launch_bounds__(256) gatherb_kernel(
        const u16* __restrict__ table, const int* __restrict__ csr,
        const int* __restrict__ endoff, const int* __restrict__ degi,
        u16* __restrict__ meanb, float* __restrict__ outp, int n_nodes) {
    int g = (blockIdx.x * 256 + threadIdx.x) >> 5;
    if (g >= n_nodes) return;
    int lane = threadIdx.x & 31;
    int slot = lane >> 3;
    int q = lane & 7;
    int end = endoff[g];
    int dg = degi[g];
    int start = end - dg;
    float4 acc = make_float4(0.f, 0.f, 0.f, 0.f);
    int k = start;
    // fast path: full 32-edge chunks, branchless (8 independent row loads in flight)
    for (; k + 32 <= end; k += 32) {
        int myid = csr[k + lane];
#pragma unroll
        for (int it = 0; it < 8; it++) {
            int nidx = (it << 2) + slot;
            int s = __shfl(myid, nidx, 32);
            ushort4 v = *reinterpret_cast<const ushort4*>(table + ((ll)s << 5) + (q << 2));
            acc.x += bf2f(v.x); acc.y += bf2f(v.y); acc.z += bf2f(v.z); acc.w += bf2f(v.w);
        }
    }
    // remainder
    if (k < end) {
        int cnt = end - k;
        int myid = (lane < cnt) ? csr[k + lane] : 0;
#pragma unroll
        for (int it = 0; it < 8; it++) {
            if ((it << 2) >= cnt) break;
            int nidx = (it << 2) + slot;
            int s = __shfl(myid, nidx, 32);
            if (nidx < cnt) {
                ushort4 v = *reinterpret_cast<const ushort4*>(table + ((ll)s << 5) + (q << 2));
                acc.x += bf2f(v.x); acc.y += bf2f(v.y); acc.z += bf2f(v.z); acc.w += bf2f(v.w);
            }
        }
    }
#pragma unroll
    for (int m = 8; m <= 16; m <<= 1) {
        acc.x += __shfl_xor(acc.x, m, 32);
        acc.y += __shfl_xor(acc.y, m, 32);
        acc.z += __shfl_xor(acc.z, m, 32);
        acc.w += __shfl_xor(acc.w, m, 32);
    }
    float dinv = dg > 0 ? 1.0f / (float)dg : 0.0f;
    if (FIN == 0) {
        if (lane < 8) {
            ushort4 r;
            r.x = f2bf(acc.x * dinv); r.y = f2bf(acc.y * dinv);
            r.z = f2bf(acc.z * dinv); r.w = f2bf(acc.w * dinv);
            *reinterpret_cast<ushort4*>(meanb + ((ll)g << 5) + (q << 2)) = r;
        }
    } else {
        if (lane < 8) {
            float4 v = make_float4(0.f, 0.f, 0.f, 0.f);
            if (q < 6) {
                v = *(reinterpret_cast<float4*>(outp + (ll)g * 24) + q);
                v.x += acc.x * dinv; v.y += acc.y * dinv; v.z += acc.z * dinv; v.w += acc.w * dinv;
            }
            float vm = (q < 6) ? fmaxf(fmaxf(v.x, v.y), fmaxf(v.z, v.w)) : -INFINITY;
#pragma unroll
            for (int m = 1; m <= 4; m <<= 1) vm = fmaxf(vm, __shfl_xor(vm, m, 32));
            float es = (q < 6) ? (expf(v.x - vm) + expf(v.y - vm) + expf(v.z - vm) + expf(v.w - vm)) : 0.0f;
#pragma unroll
            for (int m = 1; m <= 4; m <<= 1) es += __shfl_xor(es, m, 32);
            if (q < 6) {
                float l = vm + logf(es);
                v.x -= l; v.y -= l; v.z -= l; v.w -= l;
                *(reinterpret_cast<float4*>(outp + (ll)g * 24) + q) = v;
            }
        }
    }
}

// ---------------- node MLP ----------------

__global__ void __launch_bounds__(256) node_mlp_kernel(
        const float* __restrict__ feat, const u16* __restrict__ meanb,
        const float* __restrict__ W1s, const float* __restrict__ W1n, const float* __restrict__ b1,
        const float* __restrict__ W2s, const float* __restrict__ W2n, const float* __restrict__ b2,
        float* __restrict__ outp, u16* __restrict__ t2b, int n_nodes) {
    __shared__ float sW1s[26 * 40];
    __shared__ float sW1n[26 * 40];
    __shared__ float sW2s[40 * 24];
    __shared__ float sW2n[40 * 24];
    __shared__ float sb1[40];
    __shared__ float sb2[24];
    int t = threadIdx.x;
    for (int i = t; i < 26 * 40; i += 256) { sW1s[i] = W1s[i]; sW1n[i] = W1n[i]; }
    for (int i = t; i < 40 * 24; i += 256) { sW2s[i] = W2s[i]; sW2n[i] = W2n[i]; }
    if (t < 40) sb1[t] = b1[t];
    if (t < 24) sb2[t] = b2[t];
    __syncthreads();

    int n = blockIdx.x * 256 + t;
    if (n >= n_nodes) return;

    float h[40];
#pragma unroll
    for (int j = 0; j < 40; j++) h[j] = sb1[j];

    const float* fr = feat + (ll)n * 26;
    const u16* br = meanb + ((ll)n << 5);
#pragma unroll
    for (int k = 0; k < 26; k++) {
        float f = fr[k];
        float a = bf2f(br[k]);
#pragma unroll
        for (int j = 0; j < 40; j++) h[j] += f * sW1s[k * 40 + j] + a * sW1n[k * 40 + j];
    }
#pragma unroll
    for (int j = 0; j < 40; j++) h[j] = h[j] > 0.0f ? h[j] : 0.0f;

    float o[24], tt[24];
#pragma unroll
    for (int j = 0; j < 24; j++) { o[j] = sb2[j]; tt[j] = 0.0f; }
#pragma unroll
    for (int k = 0; k < 40; k++) {
        float hv = h[k];
#pragma unroll
        for (int j = 0; j < 24; j++) {
            o[j]  += hv * sW2s[k * 24 + j];
            tt[j] += hv * sW2n[k * 24 + j];
        }
    }
    float* op = outp + (ll)n * 24;
#pragma unroll
    for (int j = 0; j < 24; j++) op[j] = o[j];
    u16* tp = t2b + ((ll)n << 5);
#pragma unroll
    for (int j = 0; j < 24; j++) tp[j] = f2bf(tt[j]);
#pragma unroll
    for (int j = 24; j < 32; j++) tp[j] = (u16)0;  // pads must be zero: gather reads full 64B rows
}

// ---------------- fallback path (round-2 proven) ----------------

__global__ void hist_kernel(const int* __restrict__ dst, int* __restrict__ degi, int n_edges) {
    int i = blockIdx.x * blockDim.x + threadIdx.x;
    int base = i * 4;
    if (base + 3 < n_edges) {
        int4 d = *reinterpret_cast<const int4*>(dst + base);
        atomicAdd(&degi[d.x], 1);
        atomicAdd(&degi[d.y], 1);
        atomicAdd(&degi[d.z], 1);
        atomicAdd(&degi[d.w], 1);
    } else {
        for (int e = base; e < n_edges; e++) atomicAdd(&degi[dst[e]], 1);
    }
}

__global__ void __launch_bounds__(256) scan1_kernel(const int* __restrict__ in, int* __restrict__ out,
                                                    int* __restrict__ bsums, int n) {
    __shared__ int lds[256];
    int t = threadIdx.x;
    int base = blockIdx.x * 2048 + t * 8;
    int v[8];
    int s = 0;
#pragma unroll
    for (int i = 0; i < 8; i++) { v[i] = (base + i < n) ? in[base + i] : 0; s += v[i]; }
    lds[t] = s;
    __syncthreads();
    for (int off = 1; off < 256; off <<= 1) {
        int tv = (t >= off) ? lds[t - off] : 0;
        __syncthreads();
        lds[t] += tv;
        __syncthreads();
    }
    int excl = lds[t] - s;
    if (t == 255) bsums[blockIdx.x] = lds[255];
    int run = excl;
#pragma unroll
    for (int i = 0; i < 8; i++) {
        if (base + i < n) out[base + i] = run;
        run += v[i];
    }
}

__global__ void __launch_bounds__(256) scan2_kernel(int* __restrict__ bsums, int nb) {
    __shared__ int lds[256];
    int t = threadIdx.x;
    int v = (t < nb) ? bsums[t] : 0;
    lds[t] = v;
    __syncthreads();
    for (int off = 1; off < 256; off <<= 1) {
        int tv = (t >= off) ? lds[t - off] : 0;
        __syncthreads();
        lds[t] += tv;
        __syncthreads();
    }
    if (t < nb) bsums[t] = lds[t] - v;
}

__global__ void scan3_kernel(int* __restrict__ out, const int* __restrict__ bsums, int n) {
    int i = blockIdx.x * blockDim.x + threadIdx.x;
    if (i < n) out[i] += bsums[i >> 11];
}

__global__ void place_kernel(const int* __restrict__ src, const int* __restrict__ dst,
                             int* __restrict__ cursor, int* __restrict__ csr, int n_edges) {
    int e = blockIdx.x * blockDim.x + threadIdx.x;
    if (e < n_edges) {
        int d = dst[e];
        int pos = atomicAdd(&cursor[d], 1);
        csr[pos] = src[e];
    }
}

__global__ void __launch_bounds__(256) gather_mean26_kernel(
        const float* __restrict__ feat, const int* __restrict__ csr,
        const int* __restrict__ endoff, const int* __restrict__ degi,
        float* __restrict__ buf, int n_nodes) {
    int g = (blockIdx.x * 256 + threadIdx.x) >> 5;
    int lane = threadIdx.x & 31;
    if (g >= n_nodes) return;
    int end = endoff[g];
    int dg = degi[g];
    int start = end - dg;
    int c = lane < 26 ? lane : 0;
    float acc = 0.0f;
    int k = start;
    while (k < end) {
        int cnt = min(end - k, 32);
        int myid = (k + lane < end) ? csr[k + lane] : 0;
#pragma unroll 4
        for (int j = 0; j < cnt; j++) {
            int s = __shfl(myid, j, 32);
            acc += feat[(ll)s * 26 + c];
        }
        k += cnt;
    }
    float dinv = dg > 0 ? 1.0f / (float)dg : 0.0f;
    if (lane < 26) buf[(ll)g * 26 + lane] = acc * dinv;
}

__global__ void __launch_bounds__(256) node_mlp_fb_kernel(
        const float* __restrict__ feat, float* buf,
        const float* __restrict__ W1s, const float* __restrict__ W1n, const float* __restrict__ b1,
        const float* __restrict__ W2s, const float* __restrict__ W2n, const float* __restrict__ b2,
        float* __restrict__ outp, int n_nodes) {
    __shared__ float sW1s[26 * 40];
    __shared__ float sW1n[26 * 40];
    __shared__ float sW2s[40 * 24];
    __shared__ float sW2n[40 * 24];
    __shared__ float sb1[40];
    __shared__ float sb2[24];
    int t = threadIdx.x;
    for (int i = t; i < 26 * 40; i += 256) { sW1s[i] = W1s[i]; sW1n[i] = W1n[i]; }
    for (int i = t; i < 40 * 24; i += 256) { sW2s[i] = W2s[i]; sW2n[i] = W2n[i]; }
    if (t < 40) sb1[t] = b1[t];
    if (t < 24) sb2[t] = b2[t];
    __syncthreads();
    int n = blockIdx.x * 256 + t;
    if (n >= n_nodes) return;
    float h[40];
#pragma unroll
    for (int j = 0; j < 40; j++) h[j] = sb1[j];
    const float* fr = feat + (ll)n * 26;
    float* br = buf + (ll)n * 26;
#pragma unroll
    for (int k = 0; k < 26; k++) {
        float f = fr[k];
        float a = br[k];
#pragma unroll
        for (int j = 0; j < 40; j++) h[j] += f * sW1s[k * 40 + j] + a * sW1n[k * 40 + j];
    }
#pragma unroll
    for (int j = 0; j < 40; j++) h[j] = h[j] > 0.0f ? h[j] : 0.0f;
    float o[24], tt[24];
#pragma unroll
    for (int j = 0; j < 24; j++) { o[j] = sb2[j]; tt[j] = 0.0f; }
#pragma unroll
    for (int k = 0; k < 40; k++) {
        float hv = h[k];
#pragma unroll
        for (int j = 0; j < 24; j++) {
            o[j]  += hv * sW2s[k * 24 + j];
            tt[j] += hv * sW2n[k * 24 + j];
        }
    }
    float* op = outp + (ll)n * 24;
#pragma unroll
    for (int j = 0; j < 24; j++) op[j] = o[j];
#pragma unroll
    for (int j = 0; j < 24; j++) br[j] = tt[j];
}

__global__ void __launch_bounds__(256) gather_fin24_kernel(
        const float* __restrict__ buf, const int* __restrict__ csr,
        const int* __restrict__ endoff, const int* __restrict__ degi,
        float* __restrict__ outp, int n_nodes) {
    int g = (blockIdx.x * 256 + threadIdx.x) >> 5;
    int lane = threadIdx.x & 31;
    if (g >= n_nodes) return;
    int end = endoff[g];
    int dg = degi[g];
    int start = end - dg;
    int c = lane < 24 ? lane : 0;
    float acc = 0.0f;
    int k = start;
    while (k < end) {
        int cnt = min(end - k, 32);
        int myid = (k + lane < end) ? csr[k + lane] : 0;
#pragma unroll 4
        for (int j = 0; j < cnt; j++) {
            int s = __shfl(myid, j, 32);
            acc += buf[(ll)s * 26 + c];
        }
        k += cnt;
    }
    float dinv = dg > 0 ? 1.0f / (float)dg : 0.0f;
    float v = (lane < 24) ? outp[(ll)g * 24 + lane] + acc * dinv : -INFINITY;
    float m = v;
#pragma unroll
    for (int mask = 16; mask >= 1; mask >>= 1) m = fmaxf(m, __shfl_xor(m, mask, 32));
    float ex = (lane < 24) ? expf(v - m) : 0.0f;
    float ssum = ex;
#pragma unroll
    for (int mask = 16; mask >= 1; mask >>= 1) ssum += __shfl_xor(ssum, mask, 32);
    if (lane < 24) outp[(ll)g * 24 + lane] = v - m - logf(ssum);
}

// ---------------- launch ----------------

extern "C" void kernel_launch(void* const* d_in, const int* in_sizes, int n_in,
                              void* d_out, int out_size, void* d_ws, size_t ws_size,
                              hipStream_t stream) {
    const float* feat = (const float*)d_in[0];
    const int*   src  = (const int*)d_in[1];
    const int*   dst  = (const int*)d_in[2];
    const float* W1s  = (const float*)d_in[3];
    const float* W1n  = (const float*)d_in[4];
    const float* b1   = (const float*)d_in[5];
    const float* W2s  = (const float*)d_in[6];
    const float* W2n  = (const float*)d_in[7];
    const float* b2   = (const float*)d_in[8];

    int n_nodes = in_sizes[0] / 26;
    int n_edges = in_sizes[1];
    float* out = (float*)d_out;

    int NB = (n_nodes + BNODES - 1) >> BSHIFT;  // 391 for 200000

    // fast-path workspace (4B units, 16B-aligned blocks)
    size_t off = 0;
    auto alloc = [&off](size_t cnt) { size_t r = off; off += (cnt + 3) & ~(size_t)3; return r; };
    size_t o_bcnt   = alloc(512);
    size_t o_bstart = alloc(512);
    size_t o_bcur   = alloc(512);
    size_t o_ebuf   = alloc((size_t)n_edges < (size_t)n_nodes * 16 ? (size_t)n_nodes * 16
                                                                   : (size_t)n_edges);  // aliased as meanb bf16 x32
    size_t o_csr    = alloc(n_edges);
    size_t o_featb  = alloc((size_t)n_nodes * 16);  // u16 x 32 per node; aliased as t2b
    size_t o_degi   = alloc(n_nodes);
    size_t o_endo   = alloc(n_nodes);
    size_t need = off * 4;

    bool fast = (NB <= 512) && (n_nodes <= (1 << 18)) && (ws_size >= need);

    if (fast) {
        int* base    = (int*)d_ws;
        int* bcnt    = base + o_bcnt;
        int* bstart  = base + o_bstart;
        int* bcur    = base + o_bcur;
        u32* ebuf    = (u32*)(base + o_ebuf);
        int* csr     = base + o_csr;
        u16* featb   = (u16*)(base + o_featb);
        u16* t2b     = featb;                    // alias: featb dead after gatherb<0>
        u16* meanb   = (u16*)ebuf;               // alias: ebuf dead after place3
        int* degi    = base + o_degi;
        int* endoff  = base + o_endo;

        hipMemsetAsync(bcnt, 0, sizeof(int) * 512, stream);

        int nchunks = (n_edges + BCHUNK - 1) / BCHUNK;
        int fb_total = n_nodes * 32;
        int fb_blocks = (fb_total + 511) / 512;
        bhist_featb_kernel<<<nchunks + fb_blocks, 512, 0, stream>>>(
            dst, bcnt, n_edges, NB, nchunks, feat, featb, fb_total);
        bscan_kernel<<<1, 512, 0, stream>>>(bcnt, bstart, bcur, NB);

        bin_kernel<<<nchunks, 512, 0, stream>>>(src, dst, bcur, ebuf, n_edges, NB);

        place3_kernel<<<NB, 512, 0, stream>>>(ebuf, bstart, bcur, csr, degi, endoff, n_nodes);

        int gather_blocks = (n_nodes * 32 + 255) / 256;
        gatherb_kernel<0><<<gather_blocks, 256, 0, stream>>>(featb, csr, endoff, degi, meanb, nullptr, n_nodes);

        node_mlp_kernel<<<(n_nodes + 255) / 256, 256, 0, stream>>>(
            feat, meanb, W1s, W1n, b1, W2s, W2n, b2, out, t2b, n_nodes);

        gatherb_kernel<1><<<gather_blocks, 256, 0, stream>>>(t2b, csr, endoff, degi, nullptr, out, n_nodes);
    } else {
        // round-2 proven fallback
        int* degi  = (int*)d_ws;
        int* offs  = degi + n_nodes;
        int* bsums = offs + n_nodes;
        int* csr   = bsums + 256;
        float* buf = (float*)(csr + n_edges);

        hipMemsetAsync(degi, 0, sizeof(int) * (size_t)n_nodes, stream);
        {
            int work = (n_edges + 3) / 4;
            hist_kernel<<<(work + 255) / 256, 256, 0, stream>>>(dst, degi, n_edges);
        }
        int scan_blocks = (n_nodes + 2047) / 2048;
        scan1_kernel<<<scan_blocks, 256, 0, stream>>>(degi, offs, bsums, n_nodes);
        scan2_kernel<<<1, 256, 0, stream>>>(bsums, scan_blocks);
        scan3_kernel<<<(n_nodes + 255) / 256, 256, 0, stream>>>(offs, bsums, n_nodes);

        place_kernel<<<(n_edges + 255) / 256, 256, 0, stream>>>(src, dst, offs, csr, n_edges);

        int gather_blocks = (n_nodes * 32 + 255) / 256;
        gather_mean26_kernel<<<gather_blocks, 256, 0, stream>>>(feat, csr, offs, degi, buf, n_nodes);

        node_mlp_fb_kernel<<<(n_nodes + 255) / 256, 256, 0, stream>>>(
            feat, buf, W1s, W1n, b1, W2s, W2n, b2, out, n_nodes);

        gather_fin24_kernel<<<gather_blocks, 256, 0, stream>>>(buf, csr, offs, degi, out, n_nodes);
    }
}